// Round 8
// baseline (787.038 us; speedup 1.0000x reference)
//
#include <hip/hip_runtime.h>
#include <math.h>

namespace {
constexpr int B_ = 4;
constexpr int N_ = 2048;
constexpr int K_ = 48;
constexpr int MAX_REL_ = 32;
constexpr int EDGE_C_ = 128;
constexpr int NUM_PE_ = 16;
constexpr int NROWS = B_ * N_;      // 8192
constexpr int NEDGE = NROWS * K_;   // 393216
}

// ---------------- kernel 1: X4 = {coords[center]*m, m} ----------------
__global__ __launch_bounds__(256) void x_kernel(const float* __restrict__ coords,
                                                const float* __restrict__ mask,
                                                const int* __restrict__ t2ca,
                                                float4* __restrict__ X4) {
    int r = blockIdx.x * 256 + threadIdx.x;
    if (r >= NROWS) return;
    int b = r >> 11;                 // N_ = 2048
    int c = t2ca[r];
    float m = mask[r];
    const float* s = coords + ((size_t)(b * N_ + c)) * 3;
    X4[r] = make_float4(__fmul_rn(s[0], m), __fmul_rn(s[1], m),
                        __fmul_rn(s[2], m), m);
}

// ---------------- prep_a: row-means -> centered W (Wcf) + g-scaled Wg --------
// 1 block, wave-parallel row reductions.
__global__ __launch_bounds__(256) void prep_a(const float* __restrict__ edge_w,
                                              const float* __restrict__ ln_g,
                                              float* __restrict__ Wcf,
                                              float* __restrict__ Wg) {
    __shared__ float sm[33];
    const int wv = threadIdx.x >> 6;
    const int lane = threadIdx.x & 63;
    for (int r = wv; r < 33; r += 4) {
        float v = edge_w[r * 128 + lane] + edge_w[r * 128 + 64 + lane];
        #pragma unroll
        for (int off = 32; off; off >>= 1) v += __shfl_xor(v, off, 64);
        if (lane == 0) sm[r] = v * (1.0f / 128.0f);
    }
    __syncthreads();
    for (int idx = threadIdx.x; idx < 33 * 128; idx += 256) {
        int p = idx >> 7, c = idx & 127;
        float cen = edge_w[idx] - sm[p];
        Wcf[idx] = cen;
        if (p >= 16) Wg[(p - 16) * 128 + c] = cen * ln_g[c];
    }
}

// ---------------- prep_b: C1c[d,:] = (pe_w[d,:]+pe_b) @ Wcf[0:16,:] ----------
// 65 blocks x 128 threads.  Also writes C1g = C1c * ln_g.
__global__ __launch_bounds__(128) void prep_b(const float* __restrict__ pe_w,
                                              const float* __restrict__ pe_b,
                                              const float* __restrict__ Wcf,
                                              const float* __restrict__ ln_g,
                                              float* __restrict__ C1c,
                                              float* __restrict__ C1g) {
    const int d = blockIdx.x, c = threadIdx.x;
    float acc = 0.0f;
    #pragma unroll
    for (int q = 0; q < 16; ++q)
        acc = fmaf(pe_w[d * 16 + q] + pe_b[q], Wcf[q * 128 + c], acc);
    C1c[d * 128 + c] = acc;
    C1g[d * 128 + c] = acc * ln_g[c];
}

// ---------------- prep_c: variance tables, one 128-dot per thread ------------
// var(edge) = V0[d] + T12_2[d]·rbf + rbf^T A22 rbf
//           + tb*(Tb1_2[d] + A23_2·rbf) + tb^2*A33
__global__ __launch_bounds__(256) void prep_c(const float* __restrict__ Wcf,
                                              const float* __restrict__ C1c,
                                              float* __restrict__ V0,
                                              float* __restrict__ T12_2,
                                              float* __restrict__ Tb1_2,
                                              float* __restrict__ A22,
                                              float* __restrict__ A23_2,
                                              float* __restrict__ A33) {
    const int idx = blockIdx.x * 256 + threadIdx.x;
    const float* u; const float* v; float scale; float* dst;
    if (idx < 1040) {
        int d = idx >> 4, r = idx & 15;
        u = C1c + d * 128; v = Wcf + (16 + r) * 128;
        scale = 2.0f / 128.0f; dst = T12_2 + idx;
    } else if (idx < 1105) {
        int d = idx - 1040;
        u = C1c + d * 128; v = u; scale = 1.0f / 128.0f; dst = V0 + d;
    } else if (idx < 1170) {
        int d = idx - 1105;
        u = C1c + d * 128; v = Wcf + 32 * 128; scale = 2.0f / 128.0f; dst = Tb1_2 + d;
    } else if (idx < 1426) {
        int i = idx - 1170; int r = i >> 4, s = i & 15;
        u = Wcf + (16 + r) * 128; v = Wcf + (16 + s) * 128;
        scale = 1.0f / 128.0f; dst = A22 + i;
    } else if (idx < 1442) {
        int r = idx - 1426;
        u = Wcf + (16 + r) * 128; v = Wcf + 32 * 128;
        scale = 2.0f / 128.0f; dst = A23_2 + r;
    } else if (idx == 1442) {
        u = Wcf + 32 * 128; v = u; scale = 1.0f / 128.0f; dst = A33;
    } else return;
    float a = 0.0f;
    #pragma unroll 8
    for (int c = 0; c < 128; ++c) a = fmaf(u[c], v[c], a);
    *dst = a * scale;
}

// ---------------- kernel 2: masked distances + stable top-K (smallest) --------
// One wave per row; 4 rows per 256-thread block.
// X4 packed loads (1 VMEM/j) but loads-in-flight CAPPED: unroll 4 on the
// distance loop + launch_bounds min-6-waves/EU (VGPR <= 85) -- R7's full
// unroll hoisted 32 dwordx4 loads = 128 dest VGPRs = occupancy cliff.
// Register-only adjust (binary mask); radix-select exact 48th key; compact;
// wave bitonic sort of 64.
__global__ __launch_bounds__(256, 6) void knn_kernel(const float4* __restrict__ X4,
                                                     float* __restrict__ eidx_f,
                                                     float* __restrict__ dneb) {
    __shared__ unsigned s_hist[4][256];              // 4 KB
    __shared__ unsigned long long s_cbuf[4][64];     // 2 KB
    const int wv = threadIdx.x >> 6;
    const int lane = threadIdx.x & 63;
    const int row = blockIdx.x * 4 + wv;     // grid = NROWS/4
    const int b = row >> 11;

    const float4 xi = X4[row];
    const float mi = xi.w;
    const float4* Xb = X4 + (size_t)b * N_;

    // pass 1: one float4 load per j; D bits + zero-mask bits + row max
    unsigned fb[32];
    unsigned mz = 0u;
    float lmax = -INFINITY;
    #pragma unroll 4
    for (int t = 0; t < 32; ++t) {
        const int j = t * 64 + lane;
        const float4 p = Xb[j];
        float dx = __fsub_rn(xi.x, p.x);
        float dy = __fsub_rn(xi.y, p.y);
        float dz = __fsub_rn(xi.z, p.z);
        float d2 = __fmaf_rn(dz, dz, __fmaf_rn(dx, dx, __fmul_rn(dy, dy)));
        float m2 = __fmul_rn(mi, p.w);
        float dd = __fmul_rn(m2, __fsqrt_rn(__fadd_rn(d2, 1e-6f)));
        fb[t] = __float_as_uint(dd);
        if (m2 == 0.0f) mz |= (1u << t);
        lmax = fmaxf(lmax, dd);
    }
    #pragma unroll
    for (int off = 32; off; off >>= 1) lmax = fmaxf(lmax, __shfl_xor(lmax, off, 64));

    // pass 2 (register-only): adjust + bit-range for key normalization
    unsigned fmin_l = 0xFFFFFFFFu, fmax_l = 0u;
    #pragma unroll
    for (int t = 0; t < 32; ++t) {
        float adj = ((mz >> t) & 1u) ? lmax : __uint_as_float(fb[t]);
        unsigned u = __float_as_uint(adj);
        fb[t] = u;
        fmin_l = min(fmin_l, u);
        fmax_l = max(fmax_l, u);
    }
    #pragma unroll
    for (int off = 32; off; off >>= 1) {
        fmin_l = min(fmin_l, (unsigned)__shfl_xor((int)fmin_l, off, 64));
        fmax_l = max(fmax_l, (unsigned)__shfl_xor((int)fmax_l, off, 64));
    }
    const unsigned fminb = fmin_l;
    const unsigned range = fmax_l - fminb;
    const int vbits = (range == 0u) ? 0 : (32 - __clz((int)range));
    const int L = vbits + 11;
    int sh = (L > 8) ? (L - 8) : 0;

    unsigned cand = 0xFFFFFFFFu;
    int k_rem = K_;
    unsigned long long T = 0ull;

    while (true) {
        s_hist[wv][4 * lane + 0] = 0u;
        s_hist[wv][4 * lane + 1] = 0u;
        s_hist[wv][4 * lane + 2] = 0u;
        s_hist[wv][4 * lane + 3] = 0u;
        __asm__ volatile("s_waitcnt lgkmcnt(0)" ::: "memory");
        #pragma unroll
        for (int t = 0; t < 32; ++t) {
            if ((cand >> t) & 1u) {
                unsigned dig;
                if (sh >= 11) {
                    dig = ((fb[t] - fminb) >> (sh - 11)) & 255u;
                } else {
                    unsigned long long key =
                        ((unsigned long long)(fb[t] - fminb) << 11)
                        | (unsigned long long)(unsigned)(t * 64 + lane);
                    dig = (unsigned)(key >> sh) & 255u;
                }
                atomicAdd(&s_hist[wv][dig], 1u);
            }
        }
        __asm__ volatile("s_waitcnt lgkmcnt(0)" ::: "memory");
        const unsigned c0 = s_hist[wv][4 * lane + 0];
        const unsigned c1 = s_hist[wv][4 * lane + 1];
        const unsigned c2 = s_hist[wv][4 * lane + 2];
        const unsigned c3 = s_hist[wv][4 * lane + 3];
        const unsigned s4 = c0 + c1 + c2 + c3;
        unsigned inc = s4;
        #pragma unroll
        for (int off = 1; off < 64; off <<= 1) {
            unsigned o = (unsigned)__shfl_up((int)inc, off, 64);
            if (lane >= off) inc += o;
        }
        const unsigned ex = inc - s4;
        const unsigned e1 = ex + c0, e2 = e1 + c1, e3 = e2 + c2;
        const unsigned kr = (unsigned)k_rem;
        int digl = -1; unsigned below = 0u, bc = 0u;
        if (ex < kr && kr <= e1)           { digl = 4 * lane + 0; below = ex; bc = c0; }
        else if (e1 < kr && kr <= e2)      { digl = 4 * lane + 1; below = e1; bc = c1; }
        else if (e2 < kr && kr <= e3)      { digl = 4 * lane + 2; below = e2; bc = c2; }
        else if (e3 < kr && kr <= e3 + c3) { digl = 4 * lane + 3; below = e3; bc = c3; }

        unsigned long long bal = __ballot(digl >= 0);
        int src = __ffsll((long long)bal) - 1;
        const int dstar = __shfl(digl, src, 64);
        below = (unsigned)__shfl((int)below, src, 64);
        bc    = (unsigned)__shfl((int)bc, src, 64);
        k_rem -= (int)below;

        unsigned nc = 0u;
        unsigned long long myT = 0ull;
        #pragma unroll
        for (int t = 0; t < 32; ++t) {
            if ((cand >> t) & 1u) {
                unsigned long long key =
                    ((unsigned long long)(fb[t] - fminb) << 11)
                    | (unsigned long long)(unsigned)(t * 64 + lane);
                unsigned dig;
                if (sh >= 11) dig = ((fb[t] - fminb) >> (sh - 11)) & 255u;
                else          dig = (unsigned)(key >> sh) & 255u;
                if (dig == (unsigned)dstar) { nc |= (1u << t); myT = key; }
            }
        }
        cand = nc;
        if (bc == 1u || sh == 0) {
            unsigned long long b2 = __ballot(cand != 0u);
            int owner = __ffsll((long long)b2) - 1;
            T = __shfl(myT, owner, 64);
            break;
        }
        sh = (sh > 8) ? (sh - 8) : 0;
    }

    // select keys <= T (exactly 48), compact to LDS
    const unsigned Tv = (unsigned)(T >> 11);
    const unsigned Tj = (unsigned)(T & 2047u);
    unsigned selm = 0u; int scnt = 0;
    #pragma unroll
    for (int t = 0; t < 32; ++t) {
        unsigned v = fb[t] - fminb;
        unsigned j = (unsigned)(t * 64 + lane);
        if (v < Tv || (v == Tv && j <= Tj)) { selm |= (1u << t); ++scnt; }
    }
    int isc = scnt;
    #pragma unroll
    for (int off = 1; off < 64; off <<= 1) {
        int o = __shfl_up(isc, off, 64);
        if (lane >= off) isc += o;
    }
    int pos = isc - scnt;
    #pragma unroll
    for (int t = 0; t < 32; ++t) {
        if ((selm >> t) & 1u) {
            s_cbuf[wv][pos] = ((unsigned long long)(fb[t] - fminb) << 11)
                            | (unsigned long long)(unsigned)(t * 64 + lane);
            ++pos;
        }
    }
    __asm__ volatile("s_waitcnt lgkmcnt(0)" ::: "memory");
    unsigned long long kk = (lane < K_) ? s_cbuf[wv][lane] : ~0ull;

    // wave bitonic sort of 64 (ascending)
    #pragma unroll
    for (int k2 = 2; k2 <= 64; k2 <<= 1) {
        #pragma unroll
        for (int j = k2 >> 1; j > 0; j >>= 1) {
            unsigned long long o = __shfl_xor(kk, j, 64);
            const bool dirAsc = ((lane & k2) == 0);
            const bool lower = ((lane & j) == 0);
            unsigned long long mn = (kk < o) ? kk : o;
            unsigned long long mx = (kk < o) ? o : kk;
            kk = (lower == dirAsc) ? mn : mx;
        }
    }

    if (lane < K_) {
        unsigned fbits = (unsigned)(kk >> 11) + fminb;
        unsigned ji = (unsigned)(kk & 2047u);
        dneb[(size_t)row * K_ + lane] = __uint_as_float(fbits);
        eidx_f[(size_t)row * K_ + lane] = (float)ji;
    }
}

// ---------------- kernel 3: features -> centered+scaled matmul ---------------
// Full wave per edge, 2 channels/lane (float2), lean registers.  Meta
// {doff,tb,rstd} in one ds_read_b128 broadcast.  Algebraic LN (centered
// +g-scaled weights, variance via tables).  Eout stores NONTEMPORAL.
__global__ __launch_bounds__(256, 4) void edge_kernel(const float* __restrict__ eidx_f,
                                                      const float* __restrict__ dneb,
                                                      const float* __restrict__ token_bonds,
                                                      const float* __restrict__ C1g,
                                                      const float* __restrict__ Wg,
                                                      const float* __restrict__ V0,
                                                      const float* __restrict__ T12_2,
                                                      const float* __restrict__ Tb1_2,
                                                      const float* __restrict__ A22,
                                                      const float* __restrict__ A23_2,
                                                      const float* __restrict__ A33,
                                                      const float* __restrict__ ln_b,
                                                      const int* __restrict__ res_idx,
                                                      const int* __restrict__ is_lig,
                                                      float* __restrict__ Eout) {
    __shared__ float s_rbf[4][K_][20];     // 15 KB
    __shared__ float4 s_meta[4][K_];       // {doff_f, tb, rstd, 0}
    __shared__ float s_D[4][K_];
    const int tid = threadIdx.x;
    const int wv = tid >> 6;
    const int lane = tid & 63;
    const int row = blockIdx.x * 4 + wv;      // grid = NROWS/4, one row per wave
    const int b = row >> 11;

    // centered+g-scaled rbf(16)+bond(1) weight columns: 34 VGPRs
    float w0[17], w1[17];
    #pragma unroll
    for (int p = 0; p < 17; ++p) {
        float2 w = ((const float2*)Wg)[p * 64 + lane];
        w0[p] = w.x; w1[p] = w.y;
    }
    const float bb0 = ln_b[2 * lane], bb1 = ln_b[2 * lane + 1];

    const int ri = res_idx[row];
    const int li = is_lig[row];

    // ---- phase A: batched per-edge metadata (lane k owns edge k) ----
    int doff_l = 0; float tb_l = 0.0f;
    if (lane < K_) {
        const int e = row * K_ + lane;
        const int j = (int)(eidx_f[e] + 0.5f);
        const float D = dneb[e];
        const int jrow = b * N_ + j;
        const int rj = res_idx[jrow];
        const int lj = is_lig[jrow];
        float tb = token_bonds[(size_t)row * N_ + j];
        tb_l = (li | lj) ? tb : 0.0f;
        doff_l = min(max(ri - rj + MAX_REL_, 0), 2 * MAX_REL_);
        s_D[wv][lane] = D;
    }
    __syncthreads();

    // ---- phase B: all 48x16 RBF values cooperatively ----
    #pragma unroll
    for (int t = 0; t < (K_ * NUM_PE_) / 64; ++t) {
        const int idx = t * 64 + lane;
        const int k = idx >> 4, r = idx & 15;
        const float D = s_D[wv][k];
        const float mu = 2.0f + (float)r * (4.0f / 3.0f);
        const float x = (D - mu) * 0.8f;
        s_rbf[wv][k][r] = __expf(-x * x);
    }
    __syncthreads();

    // ---- phase VAR: lane k computes rstd for edge k; writes packed meta ----
    if (lane < K_) {
        float rr[16];
        const float* rb = &s_rbf[wv][lane][0];
        *(float4*)&rr[0]  = *(const float4*)&rb[0];
        *(float4*)&rr[4]  = *(const float4*)&rb[4];
        *(float4*)&rr[8]  = *(const float4*)&rb[8];
        *(float4*)&rr[12] = *(const float4*)&rb[12];
        float var = V0[doff_l];
        const float4* t12 = (const float4*)(T12_2 + doff_l * 16);
        float4 q0 = t12[0], q1 = t12[1], q2 = t12[2], q3 = t12[3];
        var = fmaf(rr[0], q0.x, var);  var = fmaf(rr[1], q0.y, var);
        var = fmaf(rr[2], q0.z, var);  var = fmaf(rr[3], q0.w, var);
        var = fmaf(rr[4], q1.x, var);  var = fmaf(rr[5], q1.y, var);
        var = fmaf(rr[6], q1.z, var);  var = fmaf(rr[7], q1.w, var);
        var = fmaf(rr[8], q2.x, var);  var = fmaf(rr[9], q2.y, var);
        var = fmaf(rr[10], q2.z, var); var = fmaf(rr[11], q2.w, var);
        var = fmaf(rr[12], q3.x, var); var = fmaf(rr[13], q3.y, var);
        var = fmaf(rr[14], q3.z, var); var = fmaf(rr[15], q3.w, var);
        #pragma unroll
        for (int r = 0; r < 16; ++r) {
            const float4* arow = (const float4*)(A22 + r * 16);
            float tr = 0.0f;
            #pragma unroll
            for (int s4 = 0; s4 < 4; ++s4) {
                float4 a = arow[s4];
                tr = fmaf(rr[s4 * 4 + 0], a.x, tr);
                tr = fmaf(rr[s4 * 4 + 1], a.y, tr);
                tr = fmaf(rr[s4 * 4 + 2], a.z, tr);
                tr = fmaf(rr[s4 * 4 + 3], a.w, tr);
            }
            var = fmaf(rr[r], tr, var);
        }
        if (tb_l != 0.0f) {
            float extra = Tb1_2[doff_l];
            #pragma unroll
            for (int r = 0; r < 16; ++r) extra = fmaf(rr[r], A23_2[r], extra);
            var = fmaf(tb_l, extra, var);
            var = fmaf(tb_l * tb_l, A33[0], var);
        }
        const float rstd = rsqrtf(var + 1e-5f);
        s_meta[wv][lane] = make_float4((float)doff_l, tb_l, rstd, 0.0f);
    }
    __syncthreads();

    // ---- phase C: 48 edges, full wave each, float2 nontemporal stores ----
    unsigned long long* outp =
        (unsigned long long*)Eout + (size_t)row * K_ * 64 + lane;
    #pragma unroll 4
    for (int k = 0; k < K_; ++k) {
        const float4 mt = s_meta[wv][k];      // broadcast ds_read_b128
        const int doffk = (int)mt.x;
        const float tbk = mt.y;
        const float rstd = mt.z;
        const float2 c1 = *(const float2*)(C1g + ((size_t)doffk << 7) + 2 * lane);

        float rr[16];
        const float* rb = &s_rbf[wv][k][0];
        *(float4*)&rr[0]  = *(const float4*)&rb[0];
        *(float4*)&rr[4]  = *(const float4*)&rb[4];
        *(float4*)&rr[8]  = *(const float4*)&rb[8];
        *(float4*)&rr[12] = *(const float4*)&rb[12];

        float ax = c1.x, ay = c1.y;
        #pragma unroll
        for (int p = 0; p < 16; ++p) {
            ax = fmaf(rr[p], w0[p], ax);
            ay = fmaf(rr[p], w1[p], ay);
        }
        if (tbk != 0.0f) {                 // wave-uniform branch, ~1% taken
            ax = fmaf(tbk, w0[16], ax);
            ay = fmaf(tbk, w1[16], ay);
        }
        union { float2 f; unsigned long long u; } cv;
        cv.f = make_float2(fmaf(ax, rstd, bb0), fmaf(ay, rstd, bb1));
        __builtin_nontemporal_store(cv.u, outp + (size_t)k * 64);
    }
}

extern "C" void kernel_launch(void* const* d_in, const int* in_sizes, int n_in,
                              void* d_out, int out_size, void* d_ws, size_t ws_size,
                              hipStream_t stream) {
    const float* coords      = (const float*)d_in[0];
    const float* mask        = (const float*)d_in[1];
    const float* token_bonds = (const float*)d_in[2];
    const float* pe_w        = (const float*)d_in[3];
    const float* pe_b        = (const float*)d_in[4];
    const float* edge_w      = (const float*)d_in[5];
    const float* ln_g        = (const float*)d_in[6];
    const float* ln_b        = (const float*)d_in[7];
    const int*   t2ca        = (const int*)d_in[8];
    const int*   res_idx     = (const int*)d_in[9];
    // d_in[10] (asym_id) unused: chain_labels = zeros in the reference
    const int*   is_lig      = (const int*)d_in[11];

    float* out    = (float*)d_out;
    float* Eout   = out;                               // NEDGE * 128
    float* eidx_f = out + (size_t)NEDGE * EDGE_C_;     // NEDGE (ints as floats)
    float* dneb   = eidx_f + NEDGE;                    // NEDGE

    // workspace layout (floats); float4-read tables kept 16B-aligned
    float4* X4  = (float4*)d_ws;                       // NROWS float4
    float* Wcf  = (float*)d_ws + (size_t)NROWS * 4;    // 33*128
    float* Wg   = Wcf + 33 * 128;                      // 17*128
    float* C1c  = Wg + 17 * 128;                       // 65*128
    float* C1g  = C1c + 65 * 128;                      // 65*128
    float* T12  = C1g + 65 * 128;                      // 1040
    float* A22  = T12 + 1040;                          // 256
    float* A23  = A22 + 256;                           // 16
    float* V0   = A23 + 16;                            // 65
    float* Tb1  = V0 + 65;                             // 65
    float* A33  = Tb1 + 65;                            // 1

    hipLaunchKernelGGL(x_kernel, dim3(NROWS / 256), dim3(256), 0, stream,
                       coords, mask, t2ca, X4);
    hipLaunchKernelGGL(prep_a, dim3(1), dim3(256), 0, stream,
                       edge_w, ln_g, Wcf, Wg);
    hipLaunchKernelGGL(prep_b, dim3(65), dim3(128), 0, stream,
                       pe_w, pe_b, Wcf, ln_g, C1c, C1g);
    hipLaunchKernelGGL(prep_c, dim3(6), dim3(256), 0, stream,
                       Wcf, C1c, V0, T12, Tb1, A22, A23, A33);
    hipLaunchKernelGGL(knn_kernel, dim3(NROWS / 4), dim3(256), 0, stream,
                       X4, eidx_f, dneb);
    hipLaunchKernelGGL(edge_kernel, dim3(NROWS / 4), dim3(256), 0, stream,
                       eidx_f, dneb, token_bonds, C1g, Wg, V0, T12, Tb1,
                       A22, A23, A33, ln_b, res_idx, is_lig, Eout);
}

// Round 9
// 368.386 us; speedup vs baseline: 2.1364x; 2.1364x over previous
//
#include <hip/hip_runtime.h>
#include <math.h>

namespace {
constexpr int B_ = 4;
constexpr int N_ = 2048;
constexpr int K_ = 48;
constexpr int MAX_REL_ = 32;
constexpr int EDGE_C_ = 128;
constexpr int NUM_PE_ = 16;
constexpr int NROWS = B_ * N_;      // 8192
constexpr int NEDGE = NROWS * K_;   // 393216
}

// ---------------- kernel 1: X = coords[center] * mask (stride-3) ----------
__global__ __launch_bounds__(256) void x_kernel(const float* __restrict__ coords,
                                                const float* __restrict__ mask,
                                                const int* __restrict__ t2ca,
                                                float* __restrict__ X) {
    int r = blockIdx.x * 256 + threadIdx.x;
    if (r >= NROWS) return;
    int b = r >> 11;                 // N_ = 2048
    int c = t2ca[r];
    float m = mask[r];
    const float* s = coords + ((size_t)(b * N_ + c)) * 3;
    X[r * 3 + 0] = __fmul_rn(s[0], m);
    X[r * 3 + 1] = __fmul_rn(s[1], m);
    X[r * 3 + 2] = __fmul_rn(s[2], m);
}

// ---------------- prep_a: row-means -> centered W (Wcf) + g-scaled Wg --------
__global__ __launch_bounds__(256) void prep_a(const float* __restrict__ edge_w,
                                              const float* __restrict__ ln_g,
                                              float* __restrict__ Wcf,
                                              float* __restrict__ Wg) {
    __shared__ float sm[33];
    const int wv = threadIdx.x >> 6;
    const int lane = threadIdx.x & 63;
    for (int r = wv; r < 33; r += 4) {
        float v = edge_w[r * 128 + lane] + edge_w[r * 128 + 64 + lane];
        #pragma unroll
        for (int off = 32; off; off >>= 1) v += __shfl_xor(v, off, 64);
        if (lane == 0) sm[r] = v * (1.0f / 128.0f);
    }
    __syncthreads();
    for (int idx = threadIdx.x; idx < 33 * 128; idx += 256) {
        int p = idx >> 7, c = idx & 127;
        float cen = edge_w[idx] - sm[p];
        Wcf[idx] = cen;
        if (p >= 16) Wg[(p - 16) * 128 + c] = cen * ln_g[c];
    }
}

// ---------------- prep_b: C1c[d,:] = (pe_w[d,:]+pe_b) @ Wcf[0:16,:] ----------
__global__ __launch_bounds__(128) void prep_b(const float* __restrict__ pe_w,
                                              const float* __restrict__ pe_b,
                                              const float* __restrict__ Wcf,
                                              const float* __restrict__ ln_g,
                                              float* __restrict__ C1c,
                                              float* __restrict__ C1g) {
    const int d = blockIdx.x, c = threadIdx.x;
    float acc = 0.0f;
    #pragma unroll
    for (int q = 0; q < 16; ++q)
        acc = fmaf(pe_w[d * 16 + q] + pe_b[q], Wcf[q * 128 + c], acc);
    C1c[d * 128 + c] = acc;
    C1g[d * 128 + c] = acc * ln_g[c];
}

// ---------------- prep_c: variance tables, one 128-dot per thread ------------
// var(edge) = V0[d] + T12_2[d]·rbf + rbf^T A22 rbf
//           + tb*(Tb1_2[d] + A23_2·rbf) + tb^2*A33
__global__ __launch_bounds__(256) void prep_c(const float* __restrict__ Wcf,
                                              const float* __restrict__ C1c,
                                              float* __restrict__ V0,
                                              float* __restrict__ T12_2,
                                              float* __restrict__ Tb1_2,
                                              float* __restrict__ A22,
                                              float* __restrict__ A23_2,
                                              float* __restrict__ A33) {
    const int idx = blockIdx.x * 256 + threadIdx.x;
    const float* u; const float* v; float scale; float* dst;
    if (idx < 1040) {
        int d = idx >> 4, r = idx & 15;
        u = C1c + d * 128; v = Wcf + (16 + r) * 128;
        scale = 2.0f / 128.0f; dst = T12_2 + idx;
    } else if (idx < 1105) {
        int d = idx - 1040;
        u = C1c + d * 128; v = u; scale = 1.0f / 128.0f; dst = V0 + d;
    } else if (idx < 1170) {
        int d = idx - 1105;
        u = C1c + d * 128; v = Wcf + 32 * 128; scale = 2.0f / 128.0f; dst = Tb1_2 + d;
    } else if (idx < 1426) {
        int i = idx - 1170; int r = i >> 4, s = i & 15;
        u = Wcf + (16 + r) * 128; v = Wcf + (16 + s) * 128;
        scale = 1.0f / 128.0f; dst = A22 + i;
    } else if (idx < 1442) {
        int r = idx - 1426;
        u = Wcf + (16 + r) * 128; v = Wcf + 32 * 128;
        scale = 2.0f / 128.0f; dst = A23_2 + r;
    } else if (idx == 1442) {
        u = Wcf + 32 * 128; v = u; scale = 1.0f / 128.0f; dst = A33;
    } else return;
    float a = 0.0f;
    #pragma unroll 8
    for (int c = 0; c < 128; ++c) a = fmaf(u[c], v[c], a);
    *dst = a * scale;
}

// ---------------- kernel 2: masked distances + stable top-K (smallest) --------
// VERBATIM R5 known-good (~70-75 us): fully-unrolled scalar loads keep fb[]
// in registers (NO partial unroll -- runtime-indexed fb goes to scratch,
// R8 lesson; NO full-unroll float4 loads -- 32 hoisted dwordx4 = 128 VGPRs,
// R7 lesson; NO launch_bounds cap).  Radix-select exact 48th key; compact;
// wave bitonic sort of 64.
__global__ __launch_bounds__(256) void knn_kernel(const float* __restrict__ X,
                                                  const float* __restrict__ mask,
                                                  float* __restrict__ eidx_f,
                                                  float* __restrict__ dneb) {
    __shared__ unsigned s_hist[4][256];              // 4 KB
    __shared__ unsigned long long s_cbuf[4][64];     // 2 KB
    const int wv = threadIdx.x >> 6;
    const int lane = threadIdx.x & 63;
    const int row = blockIdx.x * 4 + wv;     // grid = NROWS/4
    const int b = row >> 11;

    const float xi0 = X[row * 3 + 0];
    const float xi1 = X[row * 3 + 1];
    const float xi2 = X[row * 3 + 2];
    const float mi = mask[row];
    const float* Xb = X + (size_t)b * N_ * 3;
    const float* mb = mask + b * N_;

    // pass 1: D bits into fb[], row max
    unsigned fb[32];
    float lmax = -INFINITY;
    #pragma unroll
    for (int t = 0; t < 32; ++t) {
        int j = t * 64 + lane;
        float dx = __fsub_rn(xi0, Xb[j * 3 + 0]);
        float dy = __fsub_rn(xi1, Xb[j * 3 + 1]);
        float dz = __fsub_rn(xi2, Xb[j * 3 + 2]);
        float d2 = __fmaf_rn(dz, dz, __fmaf_rn(dx, dx, __fmul_rn(dy, dy)));
        float m2 = __fmul_rn(mi, mb[j]);
        float dd = __fmul_rn(m2, __fsqrt_rn(__fadd_rn(d2, 1e-6f)));
        fb[t] = __float_as_uint(dd);
        lmax = fmaxf(lmax, dd);
    }
    #pragma unroll
    for (int off = 32; off; off >>= 1) lmax = fmaxf(lmax, __shfl_xor(lmax, off, 64));

    // pass 2: fb <- bits(D_adjust); track bit-min/max for normalization
    unsigned fmin_l = 0xFFFFFFFFu, fmax_l = 0u;
    #pragma unroll
    for (int t = 0; t < 32; ++t) {
        int j = t * 64 + lane;
        float m2 = __fmul_rn(mi, mb[j]);
        float adj = __fadd_rn(__uint_as_float(fb[t]),
                              __fmul_rn(__fsub_rn(1.0f, m2), lmax));
        unsigned u = __float_as_uint(adj);
        fb[t] = u;
        fmin_l = min(fmin_l, u);
        fmax_l = max(fmax_l, u);
    }
    #pragma unroll
    for (int off = 32; off; off >>= 1) {
        fmin_l = min(fmin_l, (unsigned)__shfl_xor((int)fmin_l, off, 64));
        fmax_l = max(fmax_l, (unsigned)__shfl_xor((int)fmax_l, off, 64));
    }
    const unsigned fminb = fmin_l;
    const unsigned range = fmax_l - fminb;
    const int vbits = (range == 0u) ? 0 : (32 - __clz((int)range));
    const int L = vbits + 11;
    int sh = (L > 8) ? (L - 8) : 0;

    unsigned cand = 0xFFFFFFFFu;
    int k_rem = K_;
    unsigned long long T = 0ull;

    while (true) {
        s_hist[wv][4 * lane + 0] = 0u;
        s_hist[wv][4 * lane + 1] = 0u;
        s_hist[wv][4 * lane + 2] = 0u;
        s_hist[wv][4 * lane + 3] = 0u;
        __asm__ volatile("s_waitcnt lgkmcnt(0)" ::: "memory");
        #pragma unroll
        for (int t = 0; t < 32; ++t) {
            if ((cand >> t) & 1u) {
                unsigned dig;
                if (sh >= 11) {
                    dig = ((fb[t] - fminb) >> (sh - 11)) & 255u;
                } else {
                    unsigned long long key =
                        ((unsigned long long)(fb[t] - fminb) << 11)
                        | (unsigned long long)(unsigned)(t * 64 + lane);
                    dig = (unsigned)(key >> sh) & 255u;
                }
                atomicAdd(&s_hist[wv][dig], 1u);
            }
        }
        __asm__ volatile("s_waitcnt lgkmcnt(0)" ::: "memory");
        const unsigned c0 = s_hist[wv][4 * lane + 0];
        const unsigned c1 = s_hist[wv][4 * lane + 1];
        const unsigned c2 = s_hist[wv][4 * lane + 2];
        const unsigned c3 = s_hist[wv][4 * lane + 3];
        const unsigned s4 = c0 + c1 + c2 + c3;
        unsigned inc = s4;
        #pragma unroll
        for (int off = 1; off < 64; off <<= 1) {
            unsigned o = (unsigned)__shfl_up((int)inc, off, 64);
            if (lane >= off) inc += o;
        }
        const unsigned ex = inc - s4;
        const unsigned e1 = ex + c0, e2 = e1 + c1, e3 = e2 + c2;
        const unsigned kr = (unsigned)k_rem;
        int digl = -1; unsigned below = 0u, bc = 0u;
        if (ex < kr && kr <= e1)           { digl = 4 * lane + 0; below = ex; bc = c0; }
        else if (e1 < kr && kr <= e2)      { digl = 4 * lane + 1; below = e1; bc = c1; }
        else if (e2 < kr && kr <= e3)      { digl = 4 * lane + 2; below = e2; bc = c2; }
        else if (e3 < kr && kr <= e3 + c3) { digl = 4 * lane + 3; below = e3; bc = c3; }

        unsigned long long bal = __ballot(digl >= 0);
        int src = __ffsll((long long)bal) - 1;
        const int dstar = __shfl(digl, src, 64);
        below = (unsigned)__shfl((int)below, src, 64);
        bc    = (unsigned)__shfl((int)bc, src, 64);
        k_rem -= (int)below;

        unsigned nc = 0u;
        unsigned long long myT = 0ull;
        #pragma unroll
        for (int t = 0; t < 32; ++t) {
            if ((cand >> t) & 1u) {
                unsigned long long key =
                    ((unsigned long long)(fb[t] - fminb) << 11)
                    | (unsigned long long)(unsigned)(t * 64 + lane);
                unsigned dig;
                if (sh >= 11) dig = ((fb[t] - fminb) >> (sh - 11)) & 255u;
                else          dig = (unsigned)(key >> sh) & 255u;
                if (dig == (unsigned)dstar) { nc |= (1u << t); myT = key; }
            }
        }
        cand = nc;
        if (bc == 1u || sh == 0) {
            unsigned long long b2 = __ballot(cand != 0u);
            int owner = __ffsll((long long)b2) - 1;
            T = __shfl(myT, owner, 64);
            break;
        }
        sh = (sh > 8) ? (sh - 8) : 0;
    }

    // select keys <= T (exactly 48), compact to LDS
    const unsigned Tv = (unsigned)(T >> 11);
    const unsigned Tj = (unsigned)(T & 2047u);
    unsigned selm = 0u; int scnt = 0;
    #pragma unroll
    for (int t = 0; t < 32; ++t) {
        unsigned v = fb[t] - fminb;
        unsigned j = (unsigned)(t * 64 + lane);
        if (v < Tv || (v == Tv && j <= Tj)) { selm |= (1u << t); ++scnt; }
    }
    int isc = scnt;
    #pragma unroll
    for (int off = 1; off < 64; off <<= 1) {
        int o = __shfl_up(isc, off, 64);
        if (lane >= off) isc += o;
    }
    int pos = isc - scnt;
    #pragma unroll
    for (int t = 0; t < 32; ++t) {
        if ((selm >> t) & 1u) {
            s_cbuf[wv][pos] = ((unsigned long long)(fb[t] - fminb) << 11)
                            | (unsigned long long)(unsigned)(t * 64 + lane);
            ++pos;
        }
    }
    __asm__ volatile("s_waitcnt lgkmcnt(0)" ::: "memory");
    unsigned long long kk = (lane < K_) ? s_cbuf[wv][lane] : ~0ull;

    // wave bitonic sort of 64 (ascending)
    #pragma unroll
    for (int k2 = 2; k2 <= 64; k2 <<= 1) {
        #pragma unroll
        for (int j = k2 >> 1; j > 0; j >>= 1) {
            unsigned long long o = __shfl_xor(kk, j, 64);
            const bool dirAsc = ((lane & k2) == 0);
            const bool lower = ((lane & j) == 0);
            unsigned long long mn = (kk < o) ? kk : o;
            unsigned long long mx = (kk < o) ? o : kk;
            kk = (lower == dirAsc) ? mn : mx;
        }
    }

    if (lane < K_) {
        unsigned fbits = (unsigned)(kk >> 11) + fminb;
        unsigned ji = (unsigned)(kk & 2047u);
        dneb[(size_t)row * K_ + lane] = __uint_as_float(fbits);
        eidx_f[(size_t)row * K_ + lane] = (float)ji;
    }
}

// ---------------- kernel 3: features -> centered+scaled matmul ---------------
// (unchanged from R8: full wave per edge, float2 channels, meta in one
// ds_read_b128 broadcast, algebraic LN, nontemporal stores)
__global__ __launch_bounds__(256, 4) void edge_kernel(const float* __restrict__ eidx_f,
                                                      const float* __restrict__ dneb,
                                                      const float* __restrict__ token_bonds,
                                                      const float* __restrict__ C1g,
                                                      const float* __restrict__ Wg,
                                                      const float* __restrict__ V0,
                                                      const float* __restrict__ T12_2,
                                                      const float* __restrict__ Tb1_2,
                                                      const float* __restrict__ A22,
                                                      const float* __restrict__ A23_2,
                                                      const float* __restrict__ A33,
                                                      const float* __restrict__ ln_b,
                                                      const int* __restrict__ res_idx,
                                                      const int* __restrict__ is_lig,
                                                      float* __restrict__ Eout) {
    __shared__ float s_rbf[4][K_][20];     // 15 KB
    __shared__ float4 s_meta[4][K_];       // {doff_f, tb, rstd, 0}
    __shared__ float s_D[4][K_];
    const int tid = threadIdx.x;
    const int wv = tid >> 6;
    const int lane = tid & 63;
    const int row = blockIdx.x * 4 + wv;      // grid = NROWS/4, one row per wave
    const int b = row >> 11;

    float w0[17], w1[17];
    #pragma unroll
    for (int p = 0; p < 17; ++p) {
        float2 w = ((const float2*)Wg)[p * 64 + lane];
        w0[p] = w.x; w1[p] = w.y;
    }
    const float bb0 = ln_b[2 * lane], bb1 = ln_b[2 * lane + 1];

    const int ri = res_idx[row];
    const int li = is_lig[row];

    // ---- phase A: batched per-edge metadata (lane k owns edge k) ----
    int doff_l = 0; float tb_l = 0.0f;
    if (lane < K_) {
        const int e = row * K_ + lane;
        const int j = (int)(eidx_f[e] + 0.5f);
        const float D = dneb[e];
        const int jrow = b * N_ + j;
        const int rj = res_idx[jrow];
        const int lj = is_lig[jrow];
        float tb = token_bonds[(size_t)row * N_ + j];
        tb_l = (li | lj) ? tb : 0.0f;
        doff_l = min(max(ri - rj + MAX_REL_, 0), 2 * MAX_REL_);
        s_D[wv][lane] = D;
    }
    __syncthreads();

    // ---- phase B: all 48x16 RBF values cooperatively ----
    #pragma unroll
    for (int t = 0; t < (K_ * NUM_PE_) / 64; ++t) {
        const int idx = t * 64 + lane;
        const int k = idx >> 4, r = idx & 15;
        const float D = s_D[wv][k];
        const float mu = 2.0f + (float)r * (4.0f / 3.0f);
        const float x = (D - mu) * 0.8f;
        s_rbf[wv][k][r] = __expf(-x * x);
    }
    __syncthreads();

    // ---- phase VAR: lane k computes rstd for edge k; writes packed meta ----
    if (lane < K_) {
        float rr[16];
        const float* rb = &s_rbf[wv][lane][0];
        *(float4*)&rr[0]  = *(const float4*)&rb[0];
        *(float4*)&rr[4]  = *(const float4*)&rb[4];
        *(float4*)&rr[8]  = *(const float4*)&rb[8];
        *(float4*)&rr[12] = *(const float4*)&rb[12];
        float var = V0[doff_l];
        const float4* t12 = (const float4*)(T12_2 + doff_l * 16);
        float4 q0 = t12[0], q1 = t12[1], q2 = t12[2], q3 = t12[3];
        var = fmaf(rr[0], q0.x, var);  var = fmaf(rr[1], q0.y, var);
        var = fmaf(rr[2], q0.z, var);  var = fmaf(rr[3], q0.w, var);
        var = fmaf(rr[4], q1.x, var);  var = fmaf(rr[5], q1.y, var);
        var = fmaf(rr[6], q1.z, var);  var = fmaf(rr[7], q1.w, var);
        var = fmaf(rr[8], q2.x, var);  var = fmaf(rr[9], q2.y, var);
        var = fmaf(rr[10], q2.z, var); var = fmaf(rr[11], q2.w, var);
        var = fmaf(rr[12], q3.x, var); var = fmaf(rr[13], q3.y, var);
        var = fmaf(rr[14], q3.z, var); var = fmaf(rr[15], q3.w, var);
        #pragma unroll
        for (int r = 0; r < 16; ++r) {
            const float4* arow = (const float4*)(A22 + r * 16);
            float tr = 0.0f;
            #pragma unroll
            for (int s4 = 0; s4 < 4; ++s4) {
                float4 a = arow[s4];
                tr = fmaf(rr[s4 * 4 + 0], a.x, tr);
                tr = fmaf(rr[s4 * 4 + 1], a.y, tr);
                tr = fmaf(rr[s4 * 4 + 2], a.z, tr);
                tr = fmaf(rr[s4 * 4 + 3], a.w, tr);
            }
            var = fmaf(rr[r], tr, var);
        }
        if (tb_l != 0.0f) {
            float extra = Tb1_2[doff_l];
            #pragma unroll
            for (int r = 0; r < 16; ++r) extra = fmaf(rr[r], A23_2[r], extra);
            var = fmaf(tb_l, extra, var);
            var = fmaf(tb_l * tb_l, A33[0], var);
        }
        const float rstd = rsqrtf(var + 1e-5f);
        s_meta[wv][lane] = make_float4((float)doff_l, tb_l, rstd, 0.0f);
    }
    __syncthreads();

    // ---- phase C: 48 edges, full wave each, float2 nontemporal stores ----
    unsigned long long* outp =
        (unsigned long long*)Eout + (size_t)row * K_ * 64 + lane;
    #pragma unroll 4
    for (int k = 0; k < K_; ++k) {
        const float4 mt = s_meta[wv][k];      // broadcast ds_read_b128
        const int doffk = (int)mt.x;
        const float tbk = mt.y;
        const float rstd = mt.z;
        const float2 c1 = *(const float2*)(C1g + ((size_t)doffk << 7) + 2 * lane);

        float rr[16];
        const float* rb = &s_rbf[wv][k][0];
        *(float4*)&rr[0]  = *(const float4*)&rb[0];
        *(float4*)&rr[4]  = *(const float4*)&rb[4];
        *(float4*)&rr[8]  = *(const float4*)&rb[8];
        *(float4*)&rr[12] = *(const float4*)&rb[12];

        float ax = c1.x, ay = c1.y;
        #pragma unroll
        for (int p = 0; p < 16; ++p) {
            ax = fmaf(rr[p], w0[p], ax);
            ay = fmaf(rr[p], w1[p], ay);
        }
        if (tbk != 0.0f) {                 // wave-uniform branch, ~1% taken
            ax = fmaf(tbk, w0[16], ax);
            ay = fmaf(tbk, w1[16], ay);
        }
        union { float2 f; unsigned long long u; } cv;
        cv.f = make_float2(fmaf(ax, rstd, bb0), fmaf(ay, rstd, bb1));
        __builtin_nontemporal_store(cv.u, outp + (size_t)k * 64);
    }
}

extern "C" void kernel_launch(void* const* d_in, const int* in_sizes, int n_in,
                              void* d_out, int out_size, void* d_ws, size_t ws_size,
                              hipStream_t stream) {
    const float* coords      = (const float*)d_in[0];
    const float* mask        = (const float*)d_in[1];
    const float* token_bonds = (const float*)d_in[2];
    const float* pe_w        = (const float*)d_in[3];
    const float* pe_b        = (const float*)d_in[4];
    const float* edge_w      = (const float*)d_in[5];
    const float* ln_g        = (const float*)d_in[6];
    const float* ln_b        = (const float*)d_in[7];
    const int*   t2ca        = (const int*)d_in[8];
    const int*   res_idx     = (const int*)d_in[9];
    // d_in[10] (asym_id) unused: chain_labels = zeros in the reference
    const int*   is_lig      = (const int*)d_in[11];

    float* out    = (float*)d_out;
    float* Eout   = out;                               // NEDGE * 128
    float* eidx_f = out + (size_t)NEDGE * EDGE_C_;     // NEDGE (ints as floats)
    float* dneb   = eidx_f + NEDGE;                    // NEDGE

    // workspace layout (floats); float4-read tables 16B-aligned
    float* X    = (float*)d_ws;                        // NROWS*3 (24576)
    float* Wcf  = X + (size_t)NROWS * 3;               // 33*128
    float* Wg   = Wcf + 33 * 128;                      // 17*128
    float* C1c  = Wg + 17 * 128;                       // 65*128
    float* C1g  = C1c + 65 * 128;                      // 65*128
    float* T12  = C1g + 65 * 128;                      // 1040
    float* A22  = T12 + 1040;                          // 256
    float* A23  = A22 + 256;                           // 16
    float* V0   = A23 + 16;                            // 65
    float* Tb1  = V0 + 65;                             // 65
    float* A33  = Tb1 + 65;                            // 1

    hipLaunchKernelGGL(x_kernel, dim3(NROWS / 256), dim3(256), 0, stream,
                       coords, mask, t2ca, X);
    hipLaunchKernelGGL(prep_a, dim3(1), dim3(256), 0, stream,
                       edge_w, ln_g, Wcf, Wg);
    hipLaunchKernelGGL(prep_b, dim3(65), dim3(128), 0, stream,
                       pe_w, pe_b, Wcf, ln_g, C1c, C1g);
    hipLaunchKernelGGL(prep_c, dim3(6), dim3(256), 0, stream,
                       Wcf, C1c, V0, T12, Tb1, A22, A23, A33);
    hipLaunchKernelGGL(knn_kernel, dim3(NROWS / 4), dim3(256), 0, stream,
                       X, mask, eidx_f, dneb);
    hipLaunchKernelGGL(edge_kernel, dim3(NROWS / 4), dim3(256), 0, stream,
                       eidx_f, dneb, token_bonds, C1g, Wg, V0, T12, Tb1,
                       A22, A23, A33, ln_b, res_idx, is_lig, Eout);
}